// Round 1
// baseline (377.205 us; speedup 1.0000x reference)
//
#include <hip/hip_runtime.h>

// TripletColbertLoss: q (B,Q,D) fp32, p/n (B,K,D) fp32 -> scalar fp32
//   loss = relu(0.2 + neg_score - pos_score),  score = sum_{b,q} max_k q.d^T
// B=256 Q=256 K=512 D=128.
// Round 1: fp32 register-tiled (no fp32 MFMA on CDNA4). Accumulate the
// DIFFERENCE sum (max_p - max_n) so the global accumulation is O(1e3), not
// O(2.3e6) -> fp32 atomics are precise enough for the 2.5 abs threshold.

#define MARGIN   0.2f
#define Bdim     256
#define Qdim     256
#define Kdim     512
#define Ddim     128
#define BQ       64
#define BK       64
#define PADROW   68   // row stride (floats) for D-major tiles; 68%32=4 spreads banks, 68*4 B is 16B-aligned
#define NTHREADS 256

__global__ __launch_bounds__(NTHREADS, 2)
void colbert_diff_kernel(const float* __restrict__ qg,
                         const float* __restrict__ pg,
                         const float* __restrict__ ng,
                         float* __restrict__ sum_ws) {
    // D-major (transposed) tiles: element (j, row) at [j*PADROW + row]
    __shared__ float qs[Ddim * PADROW];
    __shared__ float dsb[Ddim * PADROW];
    __shared__ float part[NTHREADS / 16];

    const int tid = threadIdx.x;
    const int tx  = tid & 15;   // doc-column group
    const int ty  = tid >> 4;   // query-row group
    const int b   = blockIdx.y;
    const int q0  = blockIdx.x * BQ;

    // Stage q tile (64 rows x 128 dims), transposed into LDS.
    const float* qb = qg + ((size_t)b * Qdim + q0) * Ddim;
    for (int i = tid; i < BQ * Ddim; i += NTHREADS) {
        int row = i >> 7;          // / Ddim
        int j   = i & (Ddim - 1);  // % Ddim
        qs[j * PADROW + row] = qb[i];
    }

    float maxp[4], maxn[4];
#pragma unroll
    for (int r = 0; r < 4; ++r) { maxp[r] = -3e38f; maxn[r] = -3e38f; }

    for (int pass = 0; pass < 2; ++pass) {
        const float* docb = (pass == 0 ? pg : ng) + (size_t)b * Kdim * Ddim;
        for (int kt = 0; kt < Kdim / BK; ++kt) {
            __syncthreads();  // previous tile fully consumed
            const float* dt = docb + (size_t)kt * BK * Ddim;
            for (int i = tid; i < BK * Ddim; i += NTHREADS) {
                int row = i >> 7;
                int j   = i & (Ddim - 1);
                dsb[j * PADROW + row] = dt[i];
            }
            __syncthreads();

            float acc[4][4];
#pragma unroll
            for (int r = 0; r < 4; ++r)
#pragma unroll
                for (int c = 0; c < 4; ++c) acc[r][c] = 0.0f;

#pragma unroll 8
            for (int j = 0; j < Ddim; ++j) {
                const float4 qv = *(const float4*)&qs[j * PADROW + ty * 4];
                const float4 dv = *(const float4*)&dsb[j * PADROW + tx * 4];
                const float qa[4] = {qv.x, qv.y, qv.z, qv.w};
                const float da[4] = {dv.x, dv.y, dv.z, dv.w};
#pragma unroll
                for (int r = 0; r < 4; ++r)
#pragma unroll
                    for (int c = 0; c < 4; ++c)
                        acc[r][c] = fmaf(qa[r], da[c], acc[r][c]);
            }

            float* mx = (pass == 0) ? maxp : maxn;
#pragma unroll
            for (int r = 0; r < 4; ++r) {
                float m = fmaxf(fmaxf(acc[r][0], acc[r][1]),
                                fmaxf(acc[r][2], acc[r][3]));
                mx[r] = fmaxf(mx[r], m);
            }
        }
    }

    // Reduce row-maxes across the 16 tx lanes (contiguous within the wave).
#pragma unroll
    for (int off = 1; off < 16; off <<= 1) {
#pragma unroll
        for (int r = 0; r < 4; ++r) {
            maxp[r] = fmaxf(maxp[r], __shfl_xor(maxp[r], off));
            maxn[r] = fmaxf(maxn[r], __shfl_xor(maxn[r], off));
        }
    }

    if (tx == 0) {
        float s = 0.0f;
#pragma unroll
        for (int r = 0; r < 4; ++r) s += maxp[r] - maxn[r];
        part[ty] = s;
    }
    __syncthreads();
    if (tid == 0) {
        float t = 0.0f;
        for (int i = 0; i < NTHREADS / 16; ++i) t += part[i];
        atomicAdd(sum_ws, t);  // S = pos_score - neg_score
    }
}

__global__ void finalize_kernel(const float* __restrict__ sum_ws,
                                float* __restrict__ out) {
    out[0] = fmaxf(0.0f, MARGIN - sum_ws[0]);
}

extern "C" void kernel_launch(void* const* d_in, const int* in_sizes, int n_in,
                              void* d_out, int out_size, void* d_ws, size_t ws_size,
                              hipStream_t stream) {
    const float* q = (const float*)d_in[0];
    const float* p = (const float*)d_in[1];
    const float* n = (const float*)d_in[2];
    float* out = (float*)d_out;
    float* ws  = (float*)d_ws;

    hipMemsetAsync(ws, 0, sizeof(float), stream);  // harness poisons ws each call

    dim3 grid(Qdim / BQ, Bdim);  // 4 x 256 = 1024 blocks
    colbert_diff_kernel<<<grid, NTHREADS, 0, stream>>>(q, p, n, ws);
    finalize_kernel<<<1, 1, 0, stream>>>(ws, out);
}

// Round 2
// 188.840 us; speedup vs baseline: 1.9975x; 1.9975x over previous
//
#include <hip/hip_runtime.h>

// TripletColbertLoss on MFMA: q (B,Q,D), p/n (B,K,D) fp32 -> scalar.
// loss = relu(0.2 + neg - pos), score = sum_{b,q} max_k q.d
// B=256 Q=256 K=512 D=128.
//
// bf16 hi/lo split (x = hi + lo, both bf16) -> Ahi*Bhi + Ahi*Blo + Alo*Bhi on
// v_mfma_f32_16x16x32_bf16. Per-sim error ~5e-5 -> final scalar err ~0.02.
// One block per batch: all 256 q rows held in registers as A-fragments
// (hi+lo = 128 VGPR/lane), docs stream once through double-buffered LDS.
// Difference accumulation (max_p - max_n) keeps the global sum O(1e3) so
// fp32 atomics are exact enough.

#define MARGIN   0.2f
#define Bn       256
#define Qn       256
#define Kn       512
#define Dn       128
#define TN       32            // docs per B-tile
#define NT       (Kn / TN)     // 16 tiles per pass
#define BSTR     136           // doc stride in bf16 units: 272 B = 16B-aligned, bank offset 4 (2-way, free)
#define NTHREADS 256

typedef __attribute__((ext_vector_type(8))) short short8;
typedef __attribute__((ext_vector_type(4))) short short4v;
typedef __attribute__((ext_vector_type(4))) float f32x4;

__device__ __forceinline__ unsigned short f2bf(float x) {
    unsigned int u = __float_as_uint(x);
    return (unsigned short)((u + 0x7FFFu + ((u >> 16) & 1u)) >> 16);  // RNE
}
__device__ __forceinline__ float bf2f(unsigned short h) {
    return __uint_as_float(((unsigned int)h) << 16);
}

__global__ __launch_bounds__(NTHREADS, 1)
void colbert_mfma_kernel(const float* __restrict__ qg,
                         const float* __restrict__ pg,
                         const float* __restrict__ ng,
                         float* __restrict__ sum_ws) {
    __shared__ short Bs[2][2][TN * BSTR];   // [buf][hi/lo][doc*BSTR + dim]  34816 B
    __shared__ float part[4];

    const int tid  = threadIdx.x;
    const int w    = tid >> 6;          // wave 0..3 -> q rows w*64..+63
    const int lane = tid & 63;
    const int l16  = lane & 15;
    const int quad = lane >> 4;
    const int b    = blockIdx.x;

    // ---- A fragments: q rows in registers, hi/lo bf16.
    // A-frag layout (16x16x32): lane holds A[m = l16][k = quad*8 + j], j=0..7.
    short8 Ahi[4][4], Alo[4][4];        // [mi][ks]
    {
        const float* qb = qg + (size_t)b * Qn * Dn;
#pragma unroll
        for (int mi = 0; mi < 4; ++mi)
#pragma unroll
            for (int ks = 0; ks < 4; ++ks) {
                const float* src = qb + (size_t)(w * 64 + mi * 16 + l16) * Dn
                                      + ks * 32 + quad * 8;
                float4 v0 = *(const float4*)src;
                float4 v1 = *(const float4*)(src + 4);
                float x[8] = {v0.x, v0.y, v0.z, v0.w, v1.x, v1.y, v1.z, v1.w};
#pragma unroll
                for (int j = 0; j < 8; ++j) {
                    unsigned short h = f2bf(x[j]);
                    Ahi[mi][ks][j] = (short)h;
                    Alo[mi][ks][j] = (short)f2bf(x[j] - bf2f(h));
                }
            }
    }

    float maxp[4][4], maxn[4][4];       // [mi][reg] running row-max (per-lane, over this lane's doc cols)
#pragma unroll
    for (int mi = 0; mi < 4; ++mi)
#pragma unroll
        for (int r = 0; r < 4; ++r) { maxp[mi][r] = -3e38f; maxn[mi][r] = -3e38f; }

    const float* dbase0 = pg + (size_t)b * Kn * Dn;
    const float* dbase1 = ng + (size_t)b * Kn * Dn;

    // prefetch tile 0 (32 docs x 128 dims = 1024 float4, 4 per thread)
    float4 pre[4];
    {
        const float4* s4 = (const float4*)dbase0;
#pragma unroll
        for (int k = 0; k < 4; ++k) pre[k] = s4[tid + 256 * k];
    }

    int buf = 0;
    for (int t = 0; t < 2 * NT; ++t) {
        // convert tile t -> LDS[buf] (hi & lo planes)
#pragma unroll
        for (int k = 0; k < 4; ++k) {
            int i   = tid + 256 * k;
            int doc = i >> 5;          // 32 float4 per doc
            int d4  = i & 31;
            float4 v = pre[k];
            float x[4] = {v.x, v.y, v.z, v.w};
            short4v hi, lo;
#pragma unroll
            for (int j = 0; j < 4; ++j) {
                unsigned short h = f2bf(x[j]);
                hi[j] = (short)h;
                lo[j] = (short)f2bf(x[j] - bf2f(h));
            }
            *(short4v*)&Bs[buf][0][doc * BSTR + d4 * 4] = hi;
            *(short4v*)&Bs[buf][1][doc * BSTR + d4 * 4] = lo;
        }
        __syncthreads();

        // prefetch tile t+1 (in flight during the MFMA phase)
        if (t + 1 < 2 * NT) {
            int tn = t + 1;
            const float* base = (tn < NT) ? dbase0 : dbase1;
            const float4* s4 = (const float4*)(base + (size_t)(tn & (NT - 1)) * TN * Dn);
#pragma unroll
            for (int k = 0; k < 4; ++k) pre[k] = s4[tid + 256 * k];
        }

        // MFMA: acc[mi][ni] = (64 q-rows) x (32 docs), K=128, 3 split terms
        f32x4 acc[4][2];
#pragma unroll
        for (int mi = 0; mi < 4; ++mi)
#pragma unroll
            for (int ni = 0; ni < 2; ++ni) acc[mi][ni] = (f32x4){0.f, 0.f, 0.f, 0.f};

#pragma unroll
        for (int ni = 0; ni < 2; ++ni) {
            short8 bhi[4], blo[4];
#pragma unroll
            for (int ks = 0; ks < 4; ++ks) {
                int off = (ni * 16 + l16) * BSTR + ks * 32 + quad * 8;
                bhi[ks] = *(const short8*)&Bs[buf][0][off];
                blo[ks] = *(const short8*)&Bs[buf][1][off];
            }
#pragma unroll
            for (int ks = 0; ks < 4; ++ks)
#pragma unroll
                for (int mi = 0; mi < 4; ++mi) {
                    acc[mi][ni] = __builtin_amdgcn_mfma_f32_16x16x32_bf16(
                        Ahi[mi][ks], bhi[ks], acc[mi][ni], 0, 0, 0);
                    acc[mi][ni] = __builtin_amdgcn_mfma_f32_16x16x32_bf16(
                        Ahi[mi][ks], blo[ks], acc[mi][ni], 0, 0, 0);
                    acc[mi][ni] = __builtin_amdgcn_mfma_f32_16x16x32_bf16(
                        Alo[mi][ks], bhi[ks], acc[mi][ni], 0, 0, 0);
                }
        }

        // C/D layout: col(doc) = l16, row = quad*4 + reg. Update running row-max.
        if (t < NT) {
#pragma unroll
            for (int mi = 0; mi < 4; ++mi)
#pragma unroll
                for (int r = 0; r < 4; ++r)
                    maxp[mi][r] = fmaxf(maxp[mi][r], fmaxf(acc[mi][0][r], acc[mi][1][r]));
        } else {
#pragma unroll
            for (int mi = 0; mi < 4; ++mi)
#pragma unroll
                for (int r = 0; r < 4; ++r)
                    maxn[mi][r] = fmaxf(maxn[mi][r], fmaxf(acc[mi][0][r], acc[mi][1][r]));
        }
        buf ^= 1;
    }

    // cross-lane max over the 16 doc-column lanes
#pragma unroll
    for (int off = 1; off < 16; off <<= 1) {
#pragma unroll
        for (int mi = 0; mi < 4; ++mi)
#pragma unroll
            for (int r = 0; r < 4; ++r) {
                maxp[mi][r] = fmaxf(maxp[mi][r], __shfl_xor(maxp[mi][r], off));
                maxn[mi][r] = fmaxf(maxn[mi][r], __shfl_xor(maxn[mi][r], off));
            }
    }
    float s = 0.f;
#pragma unroll
    for (int mi = 0; mi < 4; ++mi)
#pragma unroll
        for (int r = 0; r < 4; ++r) s += maxp[mi][r] - maxn[mi][r];
    if (l16 != 0) s = 0.f;        // keep one copy per 16-lane group
    s += __shfl_xor(s, 16);
    s += __shfl_xor(s, 32);
    if (lane == 0) part[w] = s;
    __syncthreads();
    if (tid == 0)
        atomicAdd(sum_ws, part[0] + part[1] + part[2] + part[3]);  // S = pos - neg
}

__global__ void finalize_kernel(const float* __restrict__ sum_ws,
                                float* __restrict__ out) {
    out[0] = fmaxf(0.0f, MARGIN - sum_ws[0]);
}

extern "C" void kernel_launch(void* const* d_in, const int* in_sizes, int n_in,
                              void* d_out, int out_size, void* d_ws, size_t ws_size,
                              hipStream_t stream) {
    const float* q = (const float*)d_in[0];
    const float* p = (const float*)d_in[1];
    const float* n = (const float*)d_in[2];
    float* out = (float*)d_out;
    float* ws  = (float*)d_ws;

    hipMemsetAsync(ws, 0, sizeof(float), stream);  // ws is re-poisoned each call

    colbert_mfma_kernel<<<dim3(Bn), NTHREADS, 0, stream>>>(q, p, n, ws);
    finalize_kernel<<<1, 1, 0, stream>>>(ws, out);
}

// Round 3
// 180.289 us; speedup vs baseline: 2.0922x; 1.0474x over previous
//
#include <hip/hip_runtime.h>

// TripletColbertLoss on MFMA: q (B,Q,D), p/n (B,K,D) fp32 -> scalar.
// loss = relu(0.2 + neg - pos), score = sum_{b,q} max_k q.d
// B=256 Q=256 K=512 D=128.
//
// R3: pass-split grid (batch, p-or-n) = 512 blocks -> 2 blocks/CU, 2 waves/SIMD
// so one block's MFMA overlaps the other's loads/conversion/barrier. bf16 hi/lo
// truncation split, 3 MFMA terms spread across 4 independent accumulators.
// Per-block signed sum accumulated into ONE double via atomicAdd (exact).

#define MARGIN   0.2f
#define Bn       256
#define Qn       256
#define Kn       512
#define Dn       128
#define TN       32            // docs per tile
#define NT       (Kn / TN)     // 16 tiles
#define BSTR     136           // doc stride (bf16 units): 272 B, 16B-aligned, bank offset 4
#define NTHREADS 256

typedef __attribute__((ext_vector_type(8))) short short8;
typedef __attribute__((ext_vector_type(4))) short short4v;
typedef __attribute__((ext_vector_type(4))) float f32x4;

// Truncation split: x = hi + lo (both bf16 by bit-truncation). hi err <= 2^-8
// is captured exactly by lo; lo trunc err ~2^-17 of x. Cheap: shifts only.
__device__ __forceinline__ void split_trunc(float x, unsigned short& hi, unsigned short& lo) {
    unsigned int u = __float_as_uint(x);
    hi = (unsigned short)(u >> 16);
    float l = x - __uint_as_float(u & 0xFFFF0000u);
    lo = (unsigned short)(__float_as_uint(l) >> 16);
}

__global__ __launch_bounds__(NTHREADS, 2)
void colbert_pass_kernel(const float* __restrict__ qg,
                         const float* __restrict__ pg,
                         const float* __restrict__ ng,
                         double* __restrict__ sum_ws) {
    __shared__ short Bs[2][2][TN * BSTR];   // [buf][hi/lo][doc*BSTR + dim]  34816 B
    __shared__ float part[4];

    const int tid  = threadIdx.x;
    const int w    = tid >> 6;
    const int lane = tid & 63;
    const int l16  = lane & 15;
    const int quad = lane >> 4;
    const int b    = blockIdx.x;
    const int pass = blockIdx.y;            // 0 -> p (+), 1 -> n (-)

    const float* docb = (pass ? ng : pg) + (size_t)b * Kn * Dn;

    // Prefetch tile 0 first: get global loads in flight before A-conversion VALU.
    float4 pre[4];
    {
        const float4* s4 = (const float4*)docb;
#pragma unroll
        for (int k = 0; k < 4; ++k) pre[k] = s4[tid + 256 * k];
    }

    // ---- A fragments: 64 q-rows per wave, hi/lo bf16 in registers.
    // 16x16x32 A layout: lane holds A[m = l16][k = quad*8 + j], j=0..7.
    short8 Ahi[4][4], Alo[4][4];            // [mi][ks]
    {
        const float* qb = qg + (size_t)b * Qn * Dn;
#pragma unroll
        for (int mi = 0; mi < 4; ++mi)
#pragma unroll
            for (int ks = 0; ks < 4; ++ks) {
                const float* src = qb + (size_t)(w * 64 + mi * 16 + l16) * Dn
                                      + ks * 32 + quad * 8;
                float4 v0 = *(const float4*)src;
                float4 v1 = *(const float4*)(src + 4);
                float x[8] = {v0.x, v0.y, v0.z, v0.w, v1.x, v1.y, v1.z, v1.w};
#pragma unroll
                for (int j = 0; j < 8; ++j) {
                    unsigned short h, l;
                    split_trunc(x[j], h, l);
                    Ahi[mi][ks][j] = (short)h;
                    Alo[mi][ks][j] = (short)l;
                }
            }
    }

    float maxv[4][4];                       // [mi][reg] running row-max
#pragma unroll
    for (int mi = 0; mi < 4; ++mi)
#pragma unroll
        for (int r = 0; r < 4; ++r) maxv[mi][r] = -3e38f;

    int buf = 0;
    for (int t = 0; t < NT; ++t) {
        // convert tile t -> LDS[buf] (hi & lo planes)
#pragma unroll
        for (int k = 0; k < 4; ++k) {
            int i   = tid + 256 * k;
            int doc = i >> 5;              // 32 float4 per doc
            int d4  = i & 31;
            float4 v = pre[k];
            float x[4] = {v.x, v.y, v.z, v.w};
            short4v hi, lo;
#pragma unroll
            for (int j = 0; j < 4; ++j) {
                unsigned short h, l;
                split_trunc(x[j], h, l);
                hi[j] = (short)h;
                lo[j] = (short)l;
            }
            *(short4v*)&Bs[buf][0][doc * BSTR + d4 * 4] = hi;
            *(short4v*)&Bs[buf][1][doc * BSTR + d4 * 4] = lo;
        }
        __syncthreads();

        // prefetch tile t+1 while MFMAs run
        if (t + 1 < NT) {
            const float4* s4 = (const float4*)(docb + (size_t)(t + 1) * TN * Dn);
#pragma unroll
            for (int k = 0; k < 4; ++k) pre[k] = s4[tid + 256 * k];
        }

        f32x4 acc[4][2];
#pragma unroll
        for (int mi = 0; mi < 4; ++mi)
#pragma unroll
            for (int ni = 0; ni < 2; ++ni) acc[mi][ni] = (f32x4){0.f, 0.f, 0.f, 0.f};

#pragma unroll
        for (int ni = 0; ni < 2; ++ni) {
            short8 bhi[4], blo[4];
#pragma unroll
            for (int ks = 0; ks < 4; ++ks) {
                int off = (ni * 16 + l16) * BSTR + ks * 32 + quad * 8;
                bhi[ks] = *(const short8*)&Bs[buf][0][off];
                blo[ks] = *(const short8*)&Bs[buf][1][off];
            }
            // Spread the 3 split-terms: 4 independent accs (mi) between reuses.
#pragma unroll
            for (int ks = 0; ks < 4; ++ks) {
#pragma unroll
                for (int mi = 0; mi < 4; ++mi)
                    acc[mi][ni] = __builtin_amdgcn_mfma_f32_16x16x32_bf16(
                        Ahi[mi][ks], bhi[ks], acc[mi][ni], 0, 0, 0);
#pragma unroll
                for (int mi = 0; mi < 4; ++mi)
                    acc[mi][ni] = __builtin_amdgcn_mfma_f32_16x16x32_bf16(
                        Alo[mi][ks], bhi[ks], acc[mi][ni], 0, 0, 0);
#pragma unroll
                for (int mi = 0; mi < 4; ++mi)
                    acc[mi][ni] = __builtin_amdgcn_mfma_f32_16x16x32_bf16(
                        Ahi[mi][ks], blo[ks], acc[mi][ni], 0, 0, 0);
            }
        }

        // C/D layout: col(doc)=l16, row=quad*4+reg
#pragma unroll
        for (int mi = 0; mi < 4; ++mi)
#pragma unroll
            for (int r = 0; r < 4; ++r)
                maxv[mi][r] = fmaxf(maxv[mi][r], fmaxf(acc[mi][0][r], acc[mi][1][r]));
        buf ^= 1;
    }

    // max over the 16 doc-column lanes
#pragma unroll
    for (int off = 1; off < 16; off <<= 1)
#pragma unroll
        for (int mi = 0; mi < 4; ++mi)
#pragma unroll
            for (int r = 0; r < 4; ++r)
                maxv[mi][r] = fmaxf(maxv[mi][r], __shfl_xor(maxv[mi][r], off));

    float s = 0.f;
#pragma unroll
    for (int mi = 0; mi < 4; ++mi)
#pragma unroll
        for (int r = 0; r < 4; ++r) s += maxv[mi][r];
    if (l16 != 0) s = 0.f;                  // one copy per quad
    s += __shfl_xor(s, 16);                 // combine the 4 quads
    s += __shfl_xor(s, 32);
    if (lane == 0) part[w] = s;
    __syncthreads();
    if (tid == 0) {
        double t = (double)part[0] + part[1] + part[2] + part[3];
        atomicAdd(sum_ws, pass ? -t : t);   // S = pos - neg, exact in fp64
    }
}

__global__ void finalize_kernel(const double* __restrict__ sum_ws,
                                float* __restrict__ out) {
    out[0] = fmaxf(0.0f, MARGIN - (float)sum_ws[0]);
}

extern "C" void kernel_launch(void* const* d_in, const int* in_sizes, int n_in,
                              void* d_out, int out_size, void* d_ws, size_t ws_size,
                              hipStream_t stream) {
    const float* q = (const float*)d_in[0];
    const float* p = (const float*)d_in[1];
    const float* n = (const float*)d_in[2];
    float* out = (float*)d_out;
    double* ws = (double*)d_ws;

    hipMemsetAsync(ws, 0, sizeof(double), stream);  // ws re-poisoned each call

    colbert_pass_kernel<<<dim3(Bn, 2), NTHREADS, 0, stream>>>(q, p, n, ws);
    finalize_kernel<<<1, 1, 0, stream>>>(ws, out);
}